// Round 3
// baseline (945.671 us; speedup 1.0000x reference)
//
#include <hip/hip_runtime.h>

#define NN 100000
#define NE 3200000
#define NIN 16
#define ECH 16
#define F 10
#define FP 16          // padded node row stride = 64 B = one cache line
#define OC 32

// ---------- pass 1: histogram of dst
__global__ __launch_bounds__(256) void k_hist(const int* __restrict__ dst,
                                              int* __restrict__ cnt)
{
    int e = blockIdx.x * 256 + threadIdx.x;
    if (e < NE) atomicAdd(&cnt[dst[e]], 1);
}

// ---------- pass 2: exclusive scan of cnt -> offs (single block, 1024 threads)
__global__ __launch_bounds__(1024) void k_scan(const int* __restrict__ cnt,
                                               int* __restrict__ offs)
{
    __shared__ int wsum[16], wscan[16];
    int t = threadIdx.x;
    const int CH = (NN + 1023) / 1024;   // 98
    int begin = t * CH;
    int end = begin + CH; if (end > NN) end = NN;
    if (begin > NN) begin = NN;
    int s = 0;
    for (int i = begin; i < end; ++i) s += cnt[i];
    int lane = t & 63, w = t >> 6;
    int v = s;
    for (int d = 1; d < 64; d <<= 1) { int u = __shfl_up(v, d); if (lane >= d) v += u; }
    if (lane == 63) wsum[w] = v;
    __syncthreads();
    if (t < 16) {
        int u = wsum[t];
        for (int d = 1; d < 16; d <<= 1) { int x2 = __shfl_up(u, d); if (t >= d) u += x2; }
        wscan[t] = u;
    }
    __syncthreads();
    int ex = (w > 0 ? wscan[w - 1] : 0) + (v - s);
    int run = ex;
    for (int i = begin; i < end; ++i) { offs[i] = run; run += cnt[i]; }
    if (t == 1023) offs[NN] = NE;
}

// ---------- pass 3: place edges into CSR slots (single 8B write per edge)
__global__ __launch_bounds__(256) void k_place(
    const int* __restrict__ src, const int* __restrict__ dst,
    const int* __restrict__ offs, int* __restrict__ cursor,
    int2* __restrict__ pair)
{
    int e = blockIdx.x * 256 + threadIdx.x;
    if (e >= NE) return;
    int d = dst[e];
    int p = offs[d] + atomicAdd(&cursor[d], 1);
    pair[p] = make_int2(src[e], e);
}

// ---------- fused init: wave per node, 4 lanes per edge (1 tx per ea row)
__global__ __launch_bounds__(256) void k_init(
    const float* __restrict__ x, const float* __restrict__ ea,
    const int2* __restrict__ pair, const int* __restrict__ offs,
    const float* __restrict__ W1, const float* __restrict__ b1,
    const float* __restrict__ b2,
    const float* __restrict__ W3, const float* __restrict__ b3,
    const float* __restrict__ W4, const float* __restrict__ b4,
    float* __restrict__ base, float* __restrict__ feat)
{
    __shared__ float w1[NIN*F], w3[F*F], w4[ECH*F], bb[F], b4s[F];
    int t = threadIdx.x;
    if (t < NIN*F) w1[t] = W1[t];
    if (t < F*F)   w3[t] = W3[t];
    if (t < ECH*F) w4[t] = W4[t];
    if (t < F) { bb[t] = b1[t] + b2[t] + b3[t]; b4s[t] = b4[t]; }
    __syncthreads();

    int wid = t >> 6, l = t & 63;
    int n = blockIdx.x * 4 + wid;
    bool valid = n < NN;
    int p0 = 0, p1 = 0;
    if (valid) { p0 = offs[n]; p1 = offs[n + 1]; }
    int g = l >> 2, sub = l & 3;

    float acc[F];
#pragma unroll
    for (int j = 0; j < F; ++j) acc[j] = 0.f;

    for (int p = p0 + g; p < p1; p += 16) {
        int2 pr = pair[p];
        int eid = pr.y;
        float4 av = ((const float4*)(ea + (size_t)eid * ECH))[sub];
        float ev[F];
        int ib = sub * 4;
#pragma unroll
        for (int j = 0; j < F; ++j) {
            float s0 = fmaf(av.x, w4[(ib+0)*F + j], 0.f);
            s0 = fmaf(av.y, w4[(ib+1)*F + j], s0);
            s0 = fmaf(av.z, w4[(ib+2)*F + j], s0);
            s0 = fmaf(av.w, w4[(ib+3)*F + j], s0);
            ev[j] = s0;
        }
        // intra-group butterfly (all 4 lanes of a group share the same p)
#pragma unroll
        for (int j = 0; j < F; ++j) ev[j] += __shfl_xor(ev[j], 1);
#pragma unroll
        for (int j = 0; j < F; ++j) ev[j] += __shfl_xor(ev[j], 2);
#pragma unroll
        for (int j = 0; j < F; ++j) acc[j] += fmaxf(ev[j] + b4s[j], 0.f);
    }
    // node-level reduce over the 16 groups (all lanes converged here)
#pragma unroll
    for (int m = 4; m < 64; m <<= 1) {
#pragma unroll
        for (int j = 0; j < F; ++j) acc[j] += __shfl_xor(acc[j], m);
    }

    // finish: lane j < 10 computes output column j
    if (valid) {
        int j = l;
        if (j < F) {
            float a = bb[j];
#pragma unroll
            for (int i = 0; i < NIN; ++i)
                a = fmaf(x[(size_t)n * NIN + i], w1[i*F + j], a);
#pragma unroll
            for (int i = 0; i < F; ++i)
                a = fmaf(acc[i], w3[i*F + j], a);
            base[(size_t)n * FP + j] = a;
            feat[(size_t)n * FP + j] = fmaxf(a, 0.f);
        } else if (j < FP) {
            base[(size_t)n * FP + j] = 0.f;
            feat[(size_t)n * FP + j] = 0.f;
        }
    }
}

// ---------- propagation: wave per node, 4 lanes per edge (1 tx per feat row)
__global__ __launch_bounds__(256) void k_iter(
    const int2* __restrict__ pair, const int* __restrict__ offs,
    const float* __restrict__ featO, const float* __restrict__ base,
    const float* __restrict__ W2, float* __restrict__ featN)
{
    __shared__ float w2[F*F];
    __shared__ float sm[4][16];
    int t = threadIdx.x;
    if (t < F*F) w2[t] = W2[t];
    __syncthreads();

    int wid = t >> 6, l = t & 63;
    int n = blockIdx.x * 4 + wid;
    bool valid = n < NN;
    int p0 = 0, p1 = 0;
    if (valid) { p0 = offs[n]; p1 = offs[n + 1]; }
    int g = l >> 2, sub = l & 3;

    float4 a4 = make_float4(0.f, 0.f, 0.f, 0.f);
    for (int p = p0 + g; p < p1; p += 16) {
        int s = pair[p].x;
        float4 v = ((const float4*)(featO + (size_t)s * FP))[sub];
        a4.x += v.x; a4.y += v.y; a4.z += v.z; a4.w += v.w;
    }
#pragma unroll
    for (int m = 4; m < 64; m <<= 1) {
        a4.x += __shfl_xor(a4.x, m); a4.y += __shfl_xor(a4.y, m);
        a4.z += __shfl_xor(a4.z, m); a4.w += __shfl_xor(a4.w, m);
    }
    if (valid && l < 4) {       // g==0: lane l holds cols 4l..4l+3; add self row
        float4 sv = ((const float4*)(featO + (size_t)n * FP))[l];
        sm[wid][l*4+0] = a4.x + sv.x; sm[wid][l*4+1] = a4.y + sv.y;
        sm[wid][l*4+2] = a4.z + sv.z; sm[wid][l*4+3] = a4.w + sv.w;
    }
    __syncthreads();
    if (valid) {
        int j = l;
        if (j < F) {
            float a = base[(size_t)n * FP + j];
#pragma unroll
            for (int i = 0; i < F; ++i)
                a = fmaf(sm[wid][i], w2[i*F + j], a);
            featN[(size_t)n * FP + j] = fmaxf(a, 0.f);
        } else if (j < FP) {
            featN[(size_t)n * FP + j] = 0.f;
        }
    }
}

// ---------- column sum of feat -> gcol[10]
__global__ __launch_bounds__(256) void k_colsum(
    const float* __restrict__ feat, float* __restrict__ gcol)
{
    int n = blockIdx.x * 256 + threadIdx.x;
    float v[F];
#pragma unroll
    for (int j = 0; j < F; ++j) v[j] = 0.f;
    if (n < NN) {
        const float4* p = (const float4*)(feat + (size_t)n * FP);
        float4 v0 = p[0], v1 = p[1], v2 = p[2];
        v[0]=v0.x; v[1]=v0.y; v[2]=v0.z; v[3]=v0.w;
        v[4]=v1.x; v[5]=v1.y; v[6]=v1.z; v[7]=v1.w;
        v[8]=v2.x; v[9]=v2.y;
    }
#pragma unroll
    for (int off = 32; off > 0; off >>= 1) {
#pragma unroll
        for (int j = 0; j < F; ++j) v[j] += __shfl_down(v[j], off);
    }
    if ((threadIdx.x & 63) == 0) {
#pragma unroll
        for (int j = 0; j < F; ++j) atomicAdd(&gcol[j], v[j]);
    }
}

// ---------- tiny: g = gcol@W6+b6; gpart = relu(g)@W5[0:10] + b5
__global__ void k_gsmall(
    const float* __restrict__ gcol, const float* __restrict__ W6,
    const float* __restrict__ b6, const float* __restrict__ W5,
    const float* __restrict__ b5, float* __restrict__ gpart)
{
    __shared__ float r1[F];
    int t = threadIdx.x;
    if (t < F) {
        float acc = b6[t];
        for (int i = 0; i < F; ++i) acc = fmaf(gcol[i], W6[i*F + t], acc);
        r1[t] = acc > 0.f ? acc : 0.f;
    }
    __syncthreads();
    if (t < OC) {
        float acc = b5[t];
        for (int i = 0; i < F; ++i) acc = fmaf(r1[i], W5[i*OC + t], acc);
        gpart[t] = acc;
    }
}

// ---------- output: out = gpart + relu(feat@W7+b7) @ W5[10:20]
__global__ __launch_bounds__(256) void k_out(
    const float* __restrict__ feat, const float* __restrict__ W7,
    const float* __restrict__ b7, const float* __restrict__ W5,
    const float* __restrict__ gpart, float* __restrict__ out)
{
    __shared__ float w7[F*F], bb7[F], w5[F*OC], gp[OC];
    int t = threadIdx.x;
    if (t < F*F) w7[t] = W7[t];
    if (t < F) bb7[t] = b7[t];
    for (int i = t; i < F*OC; i += 256) w5[i] = W5[F*OC + i];   // rows 10..19
    if (t < OC) gp[t] = gpart[t];
    __syncthreads();
    int n = blockIdx.x * 256 + t;
    if (n >= NN) return;
    const float4* p = (const float4*)(feat + (size_t)n * FP);
    float4 v0 = p[0], v1 = p[1], v2 = p[2];
    float f[F] = {v0.x,v0.y,v0.z,v0.w, v1.x,v1.y,v1.z,v1.w, v2.x,v2.y};
    float h[F];
#pragma unroll
    for (int j = 0; j < F; ++j) h[j] = bb7[j];
#pragma unroll
    for (int i = 0; i < F; ++i) {
        float fi = f[i];
#pragma unroll
        for (int j = 0; j < F; ++j) h[j] = fmaf(fi, w7[i*F + j], h[j]);
    }
#pragma unroll
    for (int j = 0; j < F; ++j) h[j] = h[j] > 0.f ? h[j] : 0.f;
    float o[OC];
#pragma unroll
    for (int k = 0; k < OC; ++k) o[k] = gp[k];
#pragma unroll
    for (int j = 0; j < F; ++j) {
        float hj = h[j];
#pragma unroll
        for (int k = 0; k < OC; ++k) o[k] = fmaf(hj, w5[j*OC + k], o[k]);
    }
    float4* po = (float4*)(out + (size_t)n * OC);
#pragma unroll
    for (int k = 0; k < 8; ++k)
        po[k] = make_float4(o[4*k], o[4*k+1], o[4*k+2], o[4*k+3]);
}

extern "C" void kernel_launch(void* const* d_in, const int* in_sizes, int n_in,
                              void* d_out, int out_size, void* d_ws, size_t ws_size,
                              hipStream_t stream)
{
    const float* x   = (const float*)d_in[0];
    const int*   ei  = (const int*)d_in[1];
    const float* ea  = (const float*)d_in[2];
    const float* W1  = (const float*)d_in[3];
    const float* b1  = (const float*)d_in[4];
    const float* W2  = (const float*)d_in[5];
    const float* b2  = (const float*)d_in[6];
    const float* W3  = (const float*)d_in[7];
    const float* b3  = (const float*)d_in[8];
    const float* W4  = (const float*)d_in[9];
    const float* b4  = (const float*)d_in[10];
    const float* W5  = (const float*)d_in[11];
    const float* b5  = (const float*)d_in[12];
    const float* W6  = (const float*)d_in[13];
    const float* b6  = (const float*)d_in[14];
    const float* W7  = (const float*)d_in[15];
    const float* b7  = (const float*)d_in[16];

    const int* src = ei;            // edge_index[0]
    const int* dst = ei + NE;       // edge_index[1]

    // workspace layout (16B-aligned chunks, pair first)
    char* w = (char*)d_ws;
    int2* pair      = (int2*)w;                w += (size_t)NE * 8;        // 25.6 MB
    float* base     = (float*)w;               w += (size_t)NN * FP * 4;   // 6.4 MB
    float* featA    = (float*)w;               w += (size_t)NN * FP * 4;
    float* featB    = (float*)w;               w += (size_t)NN * FP * 4;
    int* cnt        = (int*)w;                 w += (size_t)NN * 4;        // zeroed
    int* cursor     = (int*)w;                 w += (size_t)NN * 4;        // zeroed (contiguous)
    int* offs       = (int*)w;                 w += (size_t)(NN + 16) * 4;
    float* gcol     = (float*)w;               w += 16 * 4;
    float* gpart    = (float*)w;               w += 32 * 4;

    const int EB = (NE + 255) / 256;
    const int NB = (NN + 255) / 256;
    const int WB = (NN + 3) / 4;        // wave-per-node blocks

    hipMemsetAsync(cnt, 0, (size_t)2 * NN * 4, stream);   // cnt + cursor
    hipMemsetAsync(gcol, 0, 16 * 4, stream);

    k_hist <<<EB, 256, 0, stream>>>(dst, cnt);
    k_scan <<<1, 1024, 0, stream>>>(cnt, offs);
    k_place<<<EB, 256, 0, stream>>>(src, dst, offs, cursor, pair);

    k_init <<<WB, 256, 0, stream>>>(x, ea, pair, offs,
                                    W1, b1, b2, W3, b3, W4, b4, base, featA);

    k_iter <<<WB, 256, 0, stream>>>(pair, offs, featA, base, W2, featB);
    k_iter <<<WB, 256, 0, stream>>>(pair, offs, featB, base, W2, featA);

    k_colsum<<<NB, 256, 0, stream>>>(featA, gcol);
    k_gsmall<<<1, 64, 0, stream>>>(gcol, W6, b6, W5, b5, gpart);
    k_out  <<<NB, 256, 0, stream>>>(featA, W7, b7, W5, gpart, (float*)d_out);
}

// Round 4
// 679.479 us; speedup vs baseline: 1.3918x; 1.3918x over previous
//
#include <hip/hip_runtime.h>

#define NN 100000
#define NE 3200000
#define NIN 16
#define ECH 16
#define F 10
#define FP 16          // padded node row stride = 64 B
#define OC 32
#define CSB 104        // colsum stage-1 blocks

__device__ __forceinline__ unsigned pk_bf16(float a, float b) {
    unsigned ua = __float_as_uint(a); ua = (ua + 0x7FFFu + ((ua >> 16) & 1u)) >> 16;
    unsigned ub = __float_as_uint(b); ub = (ub + 0x7FFFu + ((ub >> 16) & 1u)) >> 16;
    return ua | (ub << 16);
}
__device__ __forceinline__ float bf_lo(unsigned u) { return __uint_as_float(u << 16); }
__device__ __forceinline__ float bf_hi(unsigned u) { return __uint_as_float(u & 0xFFFF0000u); }

// ---------- pass 1: histogram of dst
__global__ __launch_bounds__(256) void k_hist(const int* __restrict__ dst,
                                              int* __restrict__ cnt)
{
    int e = blockIdx.x * 256 + threadIdx.x;
    if (e < NE) atomicAdd(&cnt[dst[e]], 1);
}

// ---------- pass 2: exclusive scan of cnt -> offs
__global__ __launch_bounds__(1024) void k_scan(const int* __restrict__ cnt,
                                               int* __restrict__ offs)
{
    __shared__ int wsum[16], wscan[16];
    int t = threadIdx.x;
    const int CH = (NN + 1023) / 1024;
    int begin = t * CH;
    int end = begin + CH; if (end > NN) end = NN;
    if (begin > NN) begin = NN;
    int s = 0;
    for (int i = begin; i < end; ++i) s += cnt[i];
    int lane = t & 63, w = t >> 6;
    int v = s;
    for (int d = 1; d < 64; d <<= 1) { int u = __shfl_up(v, d); if (lane >= d) v += u; }
    if (lane == 63) wsum[w] = v;
    __syncthreads();
    if (t < 16) {
        int u = wsum[t];
        for (int d = 1; d < 16; d <<= 1) { int x2 = __shfl_up(u, d); if (t >= d) u += x2; }
        wscan[t] = u;
    }
    __syncthreads();
    int ex = (w > 0 ? wscan[w - 1] : 0) + (v - s);
    int run = ex;
    for (int i = begin; i < end; ++i) { offs[i] = run; run += cnt[i]; }
    if (t == 1023) offs[NN] = NE;
}

// ---------- pass 3: project edge_attr (coalesced read) and scatter 32B CSR entry
// entry[2p]   = {bf16 ev[0..7]}
// entry[2p+1] = {bf16 ev[8..9], src, 0, 0}
__global__ __launch_bounds__(256) void k_placeE(
    const int* __restrict__ src, const int* __restrict__ dst,
    const float* __restrict__ ea,
    const int* __restrict__ offs, int* __restrict__ cursor,
    const float* __restrict__ W4, const float* __restrict__ b4,
    uint4* __restrict__ entry)
{
    __shared__ float w4[ECH*F], b4s[F];
    int t = threadIdx.x;
    if (t < ECH*F) w4[t] = W4[t];
    if (t < F) b4s[t] = b4[t];
    __syncthreads();
    int e = blockIdx.x * 256 + t;
    if (e >= NE) return;
    const float4* q = (const float4*)(ea + (size_t)e * ECH);
    float4 a0 = q[0], a1 = q[1], a2 = q[2], a3 = q[3];
    float av[ECH] = {a0.x,a0.y,a0.z,a0.w, a1.x,a1.y,a1.z,a1.w,
                     a2.x,a2.y,a2.z,a2.w, a3.x,a3.y,a3.z,a3.w};
    float ev[F];
#pragma unroll
    for (int j = 0; j < F; ++j) ev[j] = b4s[j];
#pragma unroll
    for (int i = 0; i < ECH; ++i) {
        float ai = av[i];
#pragma unroll
        for (int j = 0; j < F; ++j) ev[j] = fmaf(ai, w4[i*F + j], ev[j]);
    }
#pragma unroll
    for (int j = 0; j < F; ++j) ev[j] = fmaxf(ev[j], 0.f);
    int d = dst[e];
    int p = offs[d] + atomicAdd(&cursor[d], 1);
    uint4 h0 = make_uint4(pk_bf16(ev[0],ev[1]), pk_bf16(ev[2],ev[3]),
                          pk_bf16(ev[4],ev[5]), pk_bf16(ev[6],ev[7]));
    uint4 h1 = make_uint4(pk_bf16(ev[8],ev[9]), (unsigned)src[e], 0u, 0u);
    entry[2*(size_t)p]     = h0;
    entry[2*(size_t)p + 1] = h1;
}

// ---------- fused init: wave per node, lane per entry (coalesced CSR reads)
// also emits compact src_sorted for the iter passes
__global__ __launch_bounds__(256) void k_init(
    const float* __restrict__ x, const uint4* __restrict__ entry,
    const int* __restrict__ offs,
    const float* __restrict__ W1, const float* __restrict__ b1,
    const float* __restrict__ b2,
    const float* __restrict__ W3, const float* __restrict__ b3,
    int* __restrict__ src_sorted,
    float* __restrict__ base, float* __restrict__ feat)
{
    __shared__ float w1[NIN*F], w3[F*F], bb[F];
    int t = threadIdx.x;
    if (t < NIN*F) w1[t] = W1[t];
    if (t < F*F)   w3[t] = W3[t];
    if (t < F) bb[t] = b1[t] + b2[t] + b3[t];
    __syncthreads();

    int wid = t >> 6, l = t & 63;
    int n = blockIdx.x * 4 + wid;
    bool valid = n < NN;
    int p0 = 0, p1 = 0;
    if (valid) { p0 = offs[n]; p1 = offs[n + 1]; }

    float agg[F];
#pragma unroll
    for (int j = 0; j < F; ++j) agg[j] = 0.f;
    for (int p = p0 + l; p < p1; p += 64) {
        uint4 h0 = entry[2*(size_t)p];
        uint4 h1 = entry[2*(size_t)p + 1];
        agg[0] += bf_lo(h0.x); agg[1] += bf_hi(h0.x);
        agg[2] += bf_lo(h0.y); agg[3] += bf_hi(h0.y);
        agg[4] += bf_lo(h0.z); agg[5] += bf_hi(h0.z);
        agg[6] += bf_lo(h0.w); agg[7] += bf_hi(h0.w);
        agg[8] += bf_lo(h1.x); agg[9] += bf_hi(h1.x);
        src_sorted[p] = (int)h1.y;
    }
#pragma unroll
    for (int m = 1; m < 64; m <<= 1) {
#pragma unroll
        for (int j = 0; j < F; ++j) agg[j] += __shfl_xor(agg[j], m);
    }

    if (valid) {
        int j = l;
        if (j < F) {
            float a = bb[j];
#pragma unroll
            for (int i = 0; i < NIN; ++i)
                a = fmaf(x[(size_t)n * NIN + i], w1[i*F + j], a);
#pragma unroll
            for (int i = 0; i < F; ++i)
                a = fmaf(agg[i], w3[i*F + j], a);
            base[(size_t)n * FP + j] = a;
            feat[(size_t)n * FP + j] = fmaxf(a, 0.f);
        } else if (j < FP) {
            base[(size_t)n * FP + j] = 0.f;
            feat[(size_t)n * FP + j] = 0.f;
        }
    }
}

// ---------- propagation: wave per node, 4 lanes per edge
__global__ __launch_bounds__(256) void k_iter(
    const int* __restrict__ srcs, const int* __restrict__ offs,
    const float* __restrict__ featO, const float* __restrict__ base,
    const float* __restrict__ W2, float* __restrict__ featN)
{
    __shared__ float w2[F*F];
    __shared__ float sm[4][16];
    int t = threadIdx.x;
    if (t < F*F) w2[t] = W2[t];
    __syncthreads();

    int wid = t >> 6, l = t & 63;
    int n = blockIdx.x * 4 + wid;
    bool valid = n < NN;
    int p0 = 0, p1 = 0;
    if (valid) { p0 = offs[n]; p1 = offs[n + 1]; }
    int g = l >> 2, sub = l & 3;

    float4 a4 = make_float4(0.f, 0.f, 0.f, 0.f);
    for (int p = p0 + g; p < p1; p += 16) {
        int s = srcs[p];
        float4 v = ((const float4*)(featO + (size_t)s * FP))[sub];
        a4.x += v.x; a4.y += v.y; a4.z += v.z; a4.w += v.w;
    }
#pragma unroll
    for (int m = 4; m < 64; m <<= 1) {
        a4.x += __shfl_xor(a4.x, m); a4.y += __shfl_xor(a4.y, m);
        a4.z += __shfl_xor(a4.z, m); a4.w += __shfl_xor(a4.w, m);
    }
    if (valid && l < 4) {
        float4 sv = ((const float4*)(featO + (size_t)n * FP))[l];
        sm[wid][l*4+0] = a4.x + sv.x; sm[wid][l*4+1] = a4.y + sv.y;
        sm[wid][l*4+2] = a4.z + sv.z; sm[wid][l*4+3] = a4.w + sv.w;
    }
    __syncthreads();
    if (valid) {
        int j = l;
        if (j < F) {
            float a = base[(size_t)n * FP + j];
#pragma unroll
            for (int i = 0; i < F; ++i)
                a = fmaf(sm[wid][i], w2[i*F + j], a);
            featN[(size_t)n * FP + j] = fmaxf(a, 0.f);
        } else if (j < FP) {
            featN[(size_t)n * FP + j] = 0.f;
        }
    }
}

// ---------- colsum stage 1: atomic-free per-block partials
__global__ __launch_bounds__(256) void k_colsum(
    const float* __restrict__ feat, float* __restrict__ partial)
{
    __shared__ float sm[4][F];
    int t = threadIdx.x;
    float v[F];
#pragma unroll
    for (int j = 0; j < F; ++j) v[j] = 0.f;
    for (int n = blockIdx.x * 256 + t; n < NN; n += CSB * 256) {
        const float4* p = (const float4*)(feat + (size_t)n * FP);
        float4 v0 = p[0], v1 = p[1], v2 = p[2];
        v[0]+=v0.x; v[1]+=v0.y; v[2]+=v0.z; v[3]+=v0.w;
        v[4]+=v1.x; v[5]+=v1.y; v[6]+=v1.z; v[7]+=v1.w;
        v[8]+=v2.x; v[9]+=v2.y;
    }
#pragma unroll
    for (int off = 32; off > 0; off >>= 1) {
#pragma unroll
        for (int j = 0; j < F; ++j) v[j] += __shfl_down(v[j], off);
    }
    int wid = t >> 6;
    if ((t & 63) == 0) {
#pragma unroll
        for (int j = 0; j < F; ++j) sm[wid][j] = v[j];
    }
    __syncthreads();
    if (t < F) {
        float s = sm[0][t] + sm[1][t] + sm[2][t] + sm[3][t];
        partial[blockIdx.x * F + t] = s;
    }
}

// ---------- tiny: gcol = sum(partial); g = gcol@W6+b6; gpart = relu(g)@W5[0:10] + b5
__global__ void k_gsmall(
    const float* __restrict__ partial, const float* __restrict__ W6,
    const float* __restrict__ b6, const float* __restrict__ W5,
    const float* __restrict__ b5, float* __restrict__ gpart)
{
    __shared__ float gcol[F], r1[F];
    int t = threadIdx.x;
    if (t < F) {
        float s = 0.f;
        for (int b = 0; b < CSB; ++b) s += partial[b * F + t];
        gcol[t] = s;
    }
    __syncthreads();
    if (t < F) {
        float acc = b6[t];
        for (int i = 0; i < F; ++i) acc = fmaf(gcol[i], W6[i*F + t], acc);
        r1[t] = acc > 0.f ? acc : 0.f;
    }
    __syncthreads();
    if (t < OC) {
        float acc = b5[t];
        for (int i = 0; i < F; ++i) acc = fmaf(r1[i], W5[i*OC + t], acc);
        gpart[t] = acc;
    }
}

// ---------- output: out = gpart + relu(feat@W7+b7) @ W5[10:20]
__global__ __launch_bounds__(256) void k_out(
    const float* __restrict__ feat, const float* __restrict__ W7,
    const float* __restrict__ b7, const float* __restrict__ W5,
    const float* __restrict__ gpart, float* __restrict__ out)
{
    __shared__ float w7[F*F], bb7[F], w5[F*OC], gp[OC];
    int t = threadIdx.x;
    if (t < F*F) w7[t] = W7[t];
    if (t < F) bb7[t] = b7[t];
    for (int i = t; i < F*OC; i += 256) w5[i] = W5[F*OC + i];
    if (t < OC) gp[t] = gpart[t];
    __syncthreads();
    int n = blockIdx.x * 256 + t;
    if (n >= NN) return;
    const float4* p = (const float4*)(feat + (size_t)n * FP);
    float4 v0 = p[0], v1 = p[1], v2 = p[2];
    float f[F] = {v0.x,v0.y,v0.z,v0.w, v1.x,v1.y,v1.z,v1.w, v2.x,v2.y};
    float h[F];
#pragma unroll
    for (int j = 0; j < F; ++j) h[j] = bb7[j];
#pragma unroll
    for (int i = 0; i < F; ++i) {
        float fi = f[i];
#pragma unroll
        for (int j = 0; j < F; ++j) h[j] = fmaf(fi, w7[i*F + j], h[j]);
    }
#pragma unroll
    for (int j = 0; j < F; ++j) h[j] = h[j] > 0.f ? h[j] : 0.f;
    float o[OC];
#pragma unroll
    for (int k = 0; k < OC; ++k) o[k] = gp[k];
#pragma unroll
    for (int j = 0; j < F; ++j) {
        float hj = h[j];
#pragma unroll
        for (int k = 0; k < OC; ++k) o[k] = fmaf(hj, w5[j*OC + k], o[k]);
    }
    float4* po = (float4*)(out + (size_t)n * OC);
#pragma unroll
    for (int k = 0; k < 8; ++k)
        po[k] = make_float4(o[4*k], o[4*k+1], o[4*k+2], o[4*k+3]);
}

extern "C" void kernel_launch(void* const* d_in, const int* in_sizes, int n_in,
                              void* d_out, int out_size, void* d_ws, size_t ws_size,
                              hipStream_t stream)
{
    const float* x   = (const float*)d_in[0];
    const int*   ei  = (const int*)d_in[1];
    const float* ea  = (const float*)d_in[2];
    const float* W1  = (const float*)d_in[3];
    const float* b1  = (const float*)d_in[4];
    const float* W2  = (const float*)d_in[5];
    const float* b2  = (const float*)d_in[6];
    const float* W3  = (const float*)d_in[7];
    const float* b3  = (const float*)d_in[8];
    const float* W4  = (const float*)d_in[9];
    const float* b4  = (const float*)d_in[10];
    const float* W5  = (const float*)d_in[11];
    const float* b5  = (const float*)d_in[12];
    const float* W6  = (const float*)d_in[13];
    const float* b6  = (const float*)d_in[14];
    const float* W7  = (const float*)d_in[15];
    const float* b7  = (const float*)d_in[16];

    const int* src = ei;            // edge_index[0]
    const int* dst = ei + NE;       // edge_index[1]

    // workspace layout (16B-aligned chunks)
    char* w = (char*)d_ws;
    uint4* entry    = (uint4*)w;               w += (size_t)NE * 32;       // 102.4 MB
    int* src_sorted = (int*)w;                 w += (size_t)NE * 4;        // 12.8 MB
    float* base     = (float*)w;               w += (size_t)NN * FP * 4;
    float* featA    = (float*)w;               w += (size_t)NN * FP * 4;
    float* featB    = (float*)w;               w += (size_t)NN * FP * 4;
    int* cnt        = (int*)w;                 w += (size_t)NN * 4;        // zeroed
    int* cursor     = (int*)w;                 w += (size_t)NN * 4;        // zeroed (contiguous)
    int* offs       = (int*)w;                 w += (size_t)(NN + 16) * 4;
    float* partial  = (float*)w;               w += (size_t)CSB * F * 4;
    float* gpart    = (float*)w;               w += 32 * 4;

    const int EB = (NE + 255) / 256;
    const int NB = (NN + 255) / 256;
    const int WB = (NN + 3) / 4;

    hipMemsetAsync(cnt, 0, (size_t)2 * NN * 4, stream);   // cnt + cursor

    k_hist  <<<EB, 256, 0, stream>>>(dst, cnt);
    k_scan  <<<1, 1024, 0, stream>>>(cnt, offs);
    k_placeE<<<EB, 256, 0, stream>>>(src, dst, ea, offs, cursor, W4, b4, entry);

    k_init  <<<WB, 256, 0, stream>>>(x, entry, offs, W1, b1, b2, W3, b3,
                                     src_sorted, base, featA);

    k_iter  <<<WB, 256, 0, stream>>>(src_sorted, offs, featA, base, W2, featB);
    k_iter  <<<WB, 256, 0, stream>>>(src_sorted, offs, featB, base, W2, featA);

    k_colsum<<<CSB, 256, 0, stream>>>(featA, partial);
    k_gsmall<<<1, 64, 0, stream>>>(partial, W6, b6, W5, b5, gpart);
    k_out   <<<NB, 256, 0, stream>>>(featA, W7, b7, W5, gpart, (float*)d_out);
}

// Round 5
// 502.366 us; speedup vs baseline: 1.8824x; 1.3526x over previous
//
#include <hip/hip_runtime.h>

#define NN 100000
#define NE 3200000
#define NIN 16
#define ECH 16
#define F 10
#define FP 16          // padded node row stride = 64 B
#define OC 32
#define CSB 104        // colsum stage-1 blocks
#define BKSH 7         // 128 nodes per bucket
#define NBK 782        // ceil(NN / 128)
#define CH 8192        // edges per binscat block

// ---------- bucket histogram (LDS atomics, one global flush per block)
__global__ __launch_bounds__(256) void k_binhist(const int* __restrict__ dst,
                                                 int* __restrict__ bkcnt)
{
    __shared__ int lcnt[NBK];
    int t = threadIdx.x;
    for (int k = t; k < NBK; k += 256) lcnt[k] = 0;
    __syncthreads();
    for (int e = blockIdx.x * 256 + t; e < NE; e += gridDim.x * 256)
        atomicAdd(&lcnt[dst[e] >> BKSH], 1);
    __syncthreads();
    for (int k = t; k < NBK; k += 256) {
        int v = lcnt[k];
        if (v) atomicAdd(&bkcnt[k], v);
    }
}

// ---------- scan of bucket counts (single block, 1024 threads, 1 elem/thread)
__global__ __launch_bounds__(1024) void k_bkscan(const int* __restrict__ bkcnt,
                                                 int* __restrict__ bkbase,
                                                 int* __restrict__ offs)
{
    __shared__ int wsum[16], wscan[16];
    int t = threadIdx.x;
    int v = (t < NBK) ? bkcnt[t] : 0;
    int lane = t & 63, w = t >> 6;
    int inc = v;
    for (int d = 1; d < 64; d <<= 1) { int u = __shfl_up(inc, d); if (lane >= d) inc += u; }
    if (lane == 63) wsum[w] = inc;
    __syncthreads();
    if (t < 16) {
        int u = wsum[t];
        for (int d = 1; d < 16; d <<= 1) { int x2 = __shfl_up(u, d); if (t >= d) u += x2; }
        wscan[t] = u;
    }
    __syncthreads();
    int excl = inc - v + (w > 0 ? wscan[w - 1] : 0);
    if (t < NBK) bkbase[t] = excl;
    if (t == 0) { bkbase[NBK] = NE; offs[NN] = NE; }
}

// ---------- bin scatter: per-block contiguous claims -> streaming-ish writes
__global__ __launch_bounds__(256) void k_binscat(
    const int* __restrict__ src, const int* __restrict__ dst,
    const int* __restrict__ bkbase, int* __restrict__ cur,
    int* __restrict__ tmp_src, int* __restrict__ tmp_pe)
{
    __shared__ int lcnt[NBK];
    __shared__ int lbb[NBK];
    int t = threadIdx.x;
    int e0 = blockIdx.x * CH;
    int e1 = e0 + CH; if (e1 > NE) e1 = NE;
    for (int k = t; k < NBK; k += 256) lcnt[k] = 0;
    __syncthreads();
    for (int e = e0 + t; e < e1; e += 256)
        atomicAdd(&lcnt[dst[e] >> BKSH], 1);
    __syncthreads();
    for (int k = t; k < NBK; k += 256) {
        int c = lcnt[k];
        lbb[k] = c ? (bkbase[k] + atomicAdd(&cur[k], c)) : 0;
        lcnt[k] = 0;                       // reuse as local cursor
    }
    __syncthreads();
    for (int e = e0 + t; e < e1; e += 256) {
        int d = dst[e];
        int bk = d >> BKSH;
        int idx = atomicAdd(&lcnt[bk], 1);
        int pos = lbb[bk] + idx;
        tmp_src[pos] = src[e];
        tmp_pe[pos] = ((d & 127) << 22) | e;
    }
}

// ---------- per-bucket counting sort into final CSR (scatter stays in L2)
__global__ __launch_bounds__(256) void k_lsort(
    const int* __restrict__ bkbase,
    const int* __restrict__ tmp_src, const int* __restrict__ tmp_pe,
    int* __restrict__ offs, int* __restrict__ srcs, int* __restrict__ eids)
{
    __shared__ int lcnt[128];
    __shared__ int lcur[128];
    __shared__ int s0tot;
    int t = threadIdx.x;
    int b = blockIdx.x;
    int base = bkbase[b];
    int cnt = bkbase[b + 1] - base;
    int n0 = b << BKSH;
    int nodes = NN - n0; if (nodes > 128) nodes = 128;

    if (t < 128) lcnt[t] = 0;
    __syncthreads();
    for (int i = t; i < cnt; i += 256)
        atomicAdd(&lcnt[tmp_pe[base + i] >> 22], 1);
    __syncthreads();
    if (t < 128) {
        int v = lcnt[t];
        int lane = t & 63, w = t >> 6;
        int inc = v;
        for (int d = 1; d < 64; d <<= 1) { int u = __shfl_up(inc, d); if (lane >= d) inc += u; }
        if (w == 0 && lane == 63) s0tot = inc;
        __syncthreads();
        int excl = inc - v + (w == 1 ? s0tot : 0);
        lcur[t] = base + excl;
        if (t < nodes) offs[n0 + t] = base + excl;
    } else {
        __syncthreads();
    }
    __syncthreads();
    for (int i = t; i < cnt; i += 256) {
        int p = tmp_pe[base + i];
        int d = p >> 22;
        int pos = atomicAdd(&lcur[d], 1);
        srcs[pos] = tmp_src[base + i];
        eids[pos] = p & 0x3FFFFF;
    }
}

// ---------- fused init: wave/node, 4 lanes/edge, gather ea by eid (1 tx/edge)
__global__ __launch_bounds__(256) void k_init(
    const float* __restrict__ x, const float* __restrict__ ea,
    const int* __restrict__ eids, const int* __restrict__ offs,
    const float* __restrict__ W1, const float* __restrict__ b1,
    const float* __restrict__ b2,
    const float* __restrict__ W3, const float* __restrict__ b3,
    const float* __restrict__ W4, const float* __restrict__ b4,
    float* __restrict__ base, float* __restrict__ feat)
{
    __shared__ float w1[NIN*F], w3[F*F], w4[ECH*F], bb[F], b4s[F];
    int t = threadIdx.x;
    if (t < NIN*F) w1[t] = W1[t];
    if (t < F*F)   w3[t] = W3[t];
    if (t < ECH*F) w4[t] = W4[t];
    if (t < F) { bb[t] = b1[t] + b2[t] + b3[t]; b4s[t] = b4[t]; }
    __syncthreads();

    int wid = t >> 6, l = t & 63;
    int n = blockIdx.x * 4 + wid;
    bool valid = n < NN;
    int p0 = 0, p1 = 0;
    if (valid) { p0 = offs[n]; p1 = offs[n + 1]; }
    int g = l >> 2, sub = l & 3;

    float acc[F];
#pragma unroll
    for (int j = 0; j < F; ++j) acc[j] = 0.f;

    for (int p = p0 + g; p < p1; p += 16) {
        int eid = eids[p];
        float4 av = ((const float4*)(ea + (size_t)eid * ECH))[sub];
        float ev[F];
        int ib = sub * 4;
#pragma unroll
        for (int j = 0; j < F; ++j) {
            float s0 = fmaf(av.x, w4[(ib+0)*F + j], 0.f);
            s0 = fmaf(av.y, w4[(ib+1)*F + j], s0);
            s0 = fmaf(av.z, w4[(ib+2)*F + j], s0);
            s0 = fmaf(av.w, w4[(ib+3)*F + j], s0);
            ev[j] = s0;
        }
#pragma unroll
        for (int j = 0; j < F; ++j) ev[j] += __shfl_xor(ev[j], 1);
#pragma unroll
        for (int j = 0; j < F; ++j) ev[j] += __shfl_xor(ev[j], 2);
#pragma unroll
        for (int j = 0; j < F; ++j) acc[j] += fmaxf(ev[j] + b4s[j], 0.f);
    }
#pragma unroll
    for (int m = 4; m < 64; m <<= 1) {
#pragma unroll
        for (int j = 0; j < F; ++j) acc[j] += __shfl_xor(acc[j], m);
    }

    if (valid) {
        int j = l;
        if (j < F) {
            float a = bb[j];
#pragma unroll
            for (int i = 0; i < NIN; ++i)
                a = fmaf(x[(size_t)n * NIN + i], w1[i*F + j], a);
#pragma unroll
            for (int i = 0; i < F; ++i)
                a = fmaf(acc[i], w3[i*F + j], a);
            base[(size_t)n * FP + j] = a;
            feat[(size_t)n * FP + j] = fmaxf(a, 0.f);
        } else if (j < FP) {
            base[(size_t)n * FP + j] = 0.f;
            feat[(size_t)n * FP + j] = 0.f;
        }
    }
}

// ---------- propagation: wave per node, 4 lanes per edge
__global__ __launch_bounds__(256) void k_iter(
    const int* __restrict__ srcs, const int* __restrict__ offs,
    const float* __restrict__ featO, const float* __restrict__ base,
    const float* __restrict__ W2, float* __restrict__ featN)
{
    __shared__ float w2[F*F];
    __shared__ float sm[4][16];
    int t = threadIdx.x;
    if (t < F*F) w2[t] = W2[t];
    __syncthreads();

    int wid = t >> 6, l = t & 63;
    int n = blockIdx.x * 4 + wid;
    bool valid = n < NN;
    int p0 = 0, p1 = 0;
    if (valid) { p0 = offs[n]; p1 = offs[n + 1]; }
    int g = l >> 2, sub = l & 3;

    float4 a4 = make_float4(0.f, 0.f, 0.f, 0.f);
    for (int p = p0 + g; p < p1; p += 16) {
        int s = srcs[p];
        float4 v = ((const float4*)(featO + (size_t)s * FP))[sub];
        a4.x += v.x; a4.y += v.y; a4.z += v.z; a4.w += v.w;
    }
#pragma unroll
    for (int m = 4; m < 64; m <<= 1) {
        a4.x += __shfl_xor(a4.x, m); a4.y += __shfl_xor(a4.y, m);
        a4.z += __shfl_xor(a4.z, m); a4.w += __shfl_xor(a4.w, m);
    }
    if (valid && l < 4) {
        float4 sv = ((const float4*)(featO + (size_t)n * FP))[l];
        sm[wid][l*4+0] = a4.x + sv.x; sm[wid][l*4+1] = a4.y + sv.y;
        sm[wid][l*4+2] = a4.z + sv.z; sm[wid][l*4+3] = a4.w + sv.w;
    }
    __syncthreads();
    if (valid) {
        int j = l;
        if (j < F) {
            float a = base[(size_t)n * FP + j];
#pragma unroll
            for (int i = 0; i < F; ++i)
                a = fmaf(sm[wid][i], w2[i*F + j], a);
            featN[(size_t)n * FP + j] = fmaxf(a, 0.f);
        } else if (j < FP) {
            featN[(size_t)n * FP + j] = 0.f;
        }
    }
}

// ---------- colsum stage 1: atomic-free per-block partials
__global__ __launch_bounds__(256) void k_colsum(
    const float* __restrict__ feat, float* __restrict__ partial)
{
    __shared__ float sm[4][F];
    int t = threadIdx.x;
    float v[F];
#pragma unroll
    for (int j = 0; j < F; ++j) v[j] = 0.f;
    for (int n = blockIdx.x * 256 + t; n < NN; n += CSB * 256) {
        const float4* p = (const float4*)(feat + (size_t)n * FP);
        float4 v0 = p[0], v1 = p[1], v2 = p[2];
        v[0]+=v0.x; v[1]+=v0.y; v[2]+=v0.z; v[3]+=v0.w;
        v[4]+=v1.x; v[5]+=v1.y; v[6]+=v1.z; v[7]+=v1.w;
        v[8]+=v2.x; v[9]+=v2.y;
    }
#pragma unroll
    for (int off = 32; off > 0; off >>= 1) {
#pragma unroll
        for (int j = 0; j < F; ++j) v[j] += __shfl_down(v[j], off);
    }
    int wid = t >> 6;
    if ((t & 63) == 0) {
#pragma unroll
        for (int j = 0; j < F; ++j) sm[wid][j] = v[j];
    }
    __syncthreads();
    if (t < F) {
        float s = sm[0][t] + sm[1][t] + sm[2][t] + sm[3][t];
        partial[blockIdx.x * F + t] = s;
    }
}

// ---------- tiny: gcol = sum(partial); g = gcol@W6+b6; gpart = relu(g)@W5[0:10] + b5
__global__ void k_gsmall(
    const float* __restrict__ partial, const float* __restrict__ W6,
    const float* __restrict__ b6, const float* __restrict__ W5,
    const float* __restrict__ b5, float* __restrict__ gpart)
{
    __shared__ float gcol[F], r1[F];
    int t = threadIdx.x;
    if (t < F) {
        float s = 0.f;
        for (int b = 0; b < CSB; ++b) s += partial[b * F + t];
        gcol[t] = s;
    }
    __syncthreads();
    if (t < F) {
        float acc = b6[t];
        for (int i = 0; i < F; ++i) acc = fmaf(gcol[i], W6[i*F + t], acc);
        r1[t] = acc > 0.f ? acc : 0.f;
    }
    __syncthreads();
    if (t < OC) {
        float acc = b5[t];
        for (int i = 0; i < F; ++i) acc = fmaf(r1[i], W5[i*OC + t], acc);
        gpart[t] = acc;
    }
}

// ---------- output: out = gpart + relu(feat@W7+b7) @ W5[10:20]
__global__ __launch_bounds__(256) void k_out(
    const float* __restrict__ feat, const float* __restrict__ W7,
    const float* __restrict__ b7, const float* __restrict__ W5,
    const float* __restrict__ gpart, float* __restrict__ out)
{
    __shared__ float w7[F*F], bb7[F], w5[F*OC], gp[OC];
    int t = threadIdx.x;
    if (t < F*F) w7[t] = W7[t];
    if (t < F) bb7[t] = b7[t];
    for (int i = t; i < F*OC; i += 256) w5[i] = W5[F*OC + i];
    if (t < OC) gp[t] = gpart[t];
    __syncthreads();
    int n = blockIdx.x * 256 + t;
    if (n >= NN) return;
    const float4* p = (const float4*)(feat + (size_t)n * FP);
    float4 v0 = p[0], v1 = p[1], v2 = p[2];
    float f[F] = {v0.x,v0.y,v0.z,v0.w, v1.x,v1.y,v1.z,v1.w, v2.x,v2.y};
    float h[F];
#pragma unroll
    for (int j = 0; j < F; ++j) h[j] = bb7[j];
#pragma unroll
    for (int i = 0; i < F; ++i) {
        float fi = f[i];
#pragma unroll
        for (int j = 0; j < F; ++j) h[j] = fmaf(fi, w7[i*F + j], h[j]);
    }
#pragma unroll
    for (int j = 0; j < F; ++j) h[j] = h[j] > 0.f ? h[j] : 0.f;
    float o[OC];
#pragma unroll
    for (int k = 0; k < OC; ++k) o[k] = gp[k];
#pragma unroll
    for (int j = 0; j < F; ++j) {
        float hj = h[j];
#pragma unroll
        for (int k = 0; k < OC; ++k) o[k] = fmaf(hj, w5[j*OC + k], o[k]);
    }
    float4* po = (float4*)(out + (size_t)n * OC);
#pragma unroll
    for (int k = 0; k < 8; ++k)
        po[k] = make_float4(o[4*k], o[4*k+1], o[4*k+2], o[4*k+3]);
}

extern "C" void kernel_launch(void* const* d_in, const int* in_sizes, int n_in,
                              void* d_out, int out_size, void* d_ws, size_t ws_size,
                              hipStream_t stream)
{
    const float* x   = (const float*)d_in[0];
    const int*   ei  = (const int*)d_in[1];
    const float* ea  = (const float*)d_in[2];
    const float* W1  = (const float*)d_in[3];
    const float* b1  = (const float*)d_in[4];
    const float* W2  = (const float*)d_in[5];
    const float* b2  = (const float*)d_in[6];
    const float* W3  = (const float*)d_in[7];
    const float* b3  = (const float*)d_in[8];
    const float* W4  = (const float*)d_in[9];
    const float* b4  = (const float*)d_in[10];
    const float* W5  = (const float*)d_in[11];
    const float* b5  = (const float*)d_in[12];
    const float* W6  = (const float*)d_in[13];
    const float* b6  = (const float*)d_in[14];
    const float* W7  = (const float*)d_in[15];
    const float* b7  = (const float*)d_in[16];

    const int* src = ei;            // edge_index[0]
    const int* dst = ei + NE;       // edge_index[1]

    // workspace layout (16B-aligned chunks)
    char* w = (char*)d_ws;
    int* tmp_src = (int*)w;                    w += (size_t)NE * 4;        // 12.8 MB
    int* tmp_pe  = (int*)w;                    w += (size_t)NE * 4;
    int* srcs    = (int*)w;                    w += (size_t)NE * 4;
    int* eids    = (int*)w;                    w += (size_t)NE * 4;
    float* base  = (float*)w;                  w += (size_t)NN * FP * 4;   // 6.4 MB
    float* featA = (float*)w;                  w += (size_t)NN * FP * 4;
    float* featB = (float*)w;                  w += (size_t)NN * FP * 4;
    int* offs    = (int*)w;                    w += (size_t)(NN + 16) * 4;
    int* bkcnt   = (int*)w;                    w += (size_t)NBK * 4;       // zeroed
    int* cur     = (int*)w;                    w += (size_t)NBK * 4;       // zeroed (contiguous)
    int* bkbase  = (int*)w;                    w += (size_t)(NBK + 16) * 4;
    float* partial = (float*)w;                w += (size_t)CSB * F * 4;
    float* gpart = (float*)w;                  w += 32 * 4;

    const int NB = (NN + 255) / 256;
    const int WB = (NN + 3) / 4;
    const int SB = (NE + CH - 1) / CH;         // binscat blocks

    hipMemsetAsync(bkcnt, 0, (size_t)2 * NBK * 4, stream);   // bkcnt + cur

    k_binhist<<<512, 256, 0, stream>>>(dst, bkcnt);
    k_bkscan <<<1, 1024, 0, stream>>>(bkcnt, bkbase, offs);
    k_binscat<<<SB, 256, 0, stream>>>(src, dst, bkbase, cur, tmp_src, tmp_pe);
    k_lsort  <<<NBK, 256, 0, stream>>>(bkbase, tmp_src, tmp_pe, offs, srcs, eids);

    k_init   <<<WB, 256, 0, stream>>>(x, ea, eids, offs, W1, b1, b2, W3, b3,
                                      W4, b4, base, featA);

    k_iter   <<<WB, 256, 0, stream>>>(srcs, offs, featA, base, W2, featB);
    k_iter   <<<WB, 256, 0, stream>>>(srcs, offs, featB, base, W2, featA);

    k_colsum <<<CSB, 256, 0, stream>>>(featA, partial);
    k_gsmall <<<1, 64, 0, stream>>>(partial, W6, b6, W5, b5, gpart);
    k_out    <<<NB, 256, 0, stream>>>(featA, W7, b7, W5, gpart, (float*)d_out);
}